// Round 1
// baseline (69.040 us; speedup 1.0000x reference)
//
#include <hip/hip_runtime.h>
#include <stdint.h>

// out[b,i] = x[b,i] * (sum_j x[b,j] * W[i,j]) + bias[i]
//
// R6: single fused kernel (was: convert pass + gemm pass).
//  - Inputs are tiny (X 2 MiB + W 1 MiB) -> fully L2-resident in every XCD.
//    Load fp32 directly, convert to bf16 in-register with v_cvt_pk_bf16_f32
//    (1 instr per 2 elements), feed MFMA. No workspace, no second launch.
//  - Wave tile 32(m) x 16(n) -> grid 32x32 = 1024 one-wave blocks
//    = 4 waves/CU (was 2). Gemm is L2-latency-bound, not MFMA-bound;
//    doubling resident waves doubles issue/latency-hiding capacity.
//  - R5 lesson kept: more blocks > more per-block reuse at this size.
// Iteration floor context: harness re-poisons 256 MiB of ws at ~41 us
// (BW-saturated) every iter; kernel-side budget is the remaining ~23 us.

#define LATENT 512
#define BATCH  1024

typedef short bf16x8 __attribute__((ext_vector_type(8)));   // 8 bf16, 4 VGPRs
typedef float f32x4  __attribute__((ext_vector_type(4)));

// Packed RNE fp32->bf16, 2 elements per instruction. D[15:0]=bf16(lo),
// D[31:16]=bf16(hi) (same operand order as v_cvt_pkrtz_f16_f32).
__device__ __forceinline__ int cvt_pk(float lo, float hi) {
    int d;
    asm("v_cvt_pk_bf16_f32 %0, %1, %2" : "=v"(d) : "v"(lo), "v"(hi));
    return d;
}

// Load 8 contiguous fp32 and convert to a bf16x8 MFMA fragment.
__device__ __forceinline__ bf16x8 ld_cvt8(const float* __restrict__ p) {
    f32x4 v0 = ((const f32x4*)p)[0];
    f32x4 v1 = ((const f32x4*)p)[1];
    union { int i[4]; bf16x8 v; } u;
    u.i[0] = cvt_pk(v0[0], v0[1]);
    u.i[1] = cvt_pk(v0[2], v0[3]);
    u.i[2] = cvt_pk(v1[0], v1[1]);
    u.i[3] = cvt_pk(v1[2], v1[3]);
    return u.v;
}

// One wave per block. C = X . W^T on a 32(m) x 16(n) tile, fused epilogue.
// A[m=lane&15][k=q*8+j], B[n=lane&15][k=q*8+j]; rows K-contiguous.
// C/D frag: col = lane&15, row = q*4 + reg   (16x16x32 bf16 layout).
__global__ __launch_bounds__(64) void fused_kernel(
    const float* __restrict__ X, const float* __restrict__ W,
    const float* __restrict__ bias, float* __restrict__ out)
{
    const int lane = threadIdx.x;
    const int n0   = blockIdx.x * 16;    // 32 n-tiles
    const int m0   = blockIdx.y * 32;    // 32 m-tiles
    const int lrow = lane & 15;
    const int q    = lane >> 4;          // 0..3

    const float* ap0 = X + (size_t)(m0 + lrow) * LATENT + q * 8;
    const float* ap1 = ap0 + 16 * LATENT;
    const float* bp0 = W + (size_t)(n0 + lrow) * LATENT + q * 8;

    f32x4 acc[2] = {};
    #pragma unroll
    for (int ks = 0; ks < 16; ++ks) {
        bf16x8 a0 = ld_cvt8(ap0 + ks * 32);   // 128B imm offsets
        bf16x8 a1 = ld_cvt8(ap1 + ks * 32);
        bf16x8 b0 = ld_cvt8(bp0 + ks * 32);
        acc[0] = __builtin_amdgcn_mfma_f32_16x16x32_bf16(a0, b0, acc[0], 0, 0, 0);
        acc[1] = __builtin_amdgcn_mfma_f32_16x16x32_bf16(a1, b0, acc[1], 0, 0, 0);
    }

    // Epilogue in fp32: out = x * wx + bias
    const float bv = bias[n0 + lrow];
    #pragma unroll
    for (int mi = 0; mi < 2; ++mi) {
        #pragma unroll
        for (int r = 0; r < 4; ++r) {
            const int m = m0 + mi * 16 + q * 4 + r;
            const int n = n0 + lrow;
            out[(size_t)m * LATENT + n] =
                X[(size_t)m * LATENT + n] * acc[mi][r] + bv;
        }
    }
}

extern "C" void kernel_launch(void* const* d_in, const int* in_sizes, int n_in,
                              void* d_out, int out_size, void* d_ws, size_t ws_size,
                              hipStream_t stream) {
    const float* X    = (const float*)d_in[0];   // (1024, 512)
    const float* W    = (const float*)d_in[1];   // (512, 512)
    const float* bias = (const float*)d_in[2];   // (512,)
    float* out        = (float*)d_out;           // (1024, 512)
    (void)d_ws; (void)ws_size;

    fused_kernel<<<dim3(LATENT / 16, BATCH / 32), 64, 0, stream>>>(X, W, bias, out);
}

// Round 2
// 65.712 us; speedup vs baseline: 1.0506x; 1.0506x over previous
//
#include <hip/hip_runtime.h>
#include <stdint.h>

// out[b,i] = x[b,i] * (sum_j x[b,j] * W[i,j]) + bias[i]
//
// R7 = revert to R4/R0 two-phase structure (R6 single-kernel fusion REGRESSED
// +4.6us: fp32 operands tripled GEMM-phase L2/IF$ traffic and put 192 cvt_pk
// on the MFMA critical path; launch savings were negligible under graph replay).
// (1) convert X,W fp32->bf16 once into ws (each element exactly once);
// (2) LDS-free MFMA GEMM, one 64-thread block (1 wave) per tile, direct
//     global->register loads, fused fp32 epilogue.
// R7 riders on the known-good structure:
//  - 32x16 wave tile (was 32x32): 1024 blocks -> 4 waves/CU, all 4 SIMDs
//    covered (was 2); per-wave K-loop 48 loads + 32 MFMA (was 64 + 64).
//  - epilogue X/bias prefetched BEFORE the K-loop so their L2/HBM latency
//    hides under the MFMAs instead of serializing at the wave tail.
// R5 lesson kept: tile count (not reuse) is binding -> never below 512 blocks.

#define LATENT 512
#define BATCH  1024
#define XN (BATCH * LATENT)    // 524288 floats
#define WN (LATENT * LATENT)   // 262144 floats

typedef short bf16x8 __attribute__((ext_vector_type(8)));   // 8 bf16, 4 VGPRs
typedef float f32x4  __attribute__((ext_vector_type(4)));

__device__ __forceinline__ short f2bf(float f) {
    // RNE fp32 -> bf16 (finite normals)
    uint32_t u = __builtin_bit_cast(uint32_t, f);
    u += 0x7FFFu + ((u >> 16) & 1u);
    return (short)(u >> 16);
}

// ---- Kernel 1: convert X and W to bf16 in ws (each element exactly once) ----
__global__ __launch_bounds__(256) void convert_kernel(
    const float* __restrict__ X, const float* __restrict__ W,
    short* __restrict__ Xb, short* __restrict__ Wb)
{
    const int g = (blockIdx.x * 256 + threadIdx.x) * 8;
    const float* src;
    short* dst;
    if (g < XN) { src = X + g;        dst = Xb + g; }
    else        { src = W + (g - XN); dst = Wb + (g - XN); }
    f32x4 v0 = ((const f32x4*)src)[0];
    f32x4 v1 = ((const f32x4*)src)[1];
    short s[8];
    #pragma unroll
    for (int i = 0; i < 4; ++i) s[i]     = f2bf(v0[i]);
    #pragma unroll
    for (int i = 0; i < 4; ++i) s[4 + i] = f2bf(v1[i]);
    *(bf16x8*)dst = *(bf16x8*)s;
}

// ---- Kernel 2: GEMM C = Xb . Wb^T, 32(m) x 16(n) per wave, fused epilogue ----
// A[m=lane&15][k=q*8+j], B[n=lane&15][k=q*8+j]; rows K-contiguous bf16.
// C/D frag (16x16x32): col = lane&15, row = q*4 + reg.
__global__ __launch_bounds__(64) void gemm_kernel(
    const short* __restrict__ Xb, const short* __restrict__ Wb,
    const float* __restrict__ X, const float* __restrict__ bias,
    float* __restrict__ out)
{
    const int lane = threadIdx.x;       // one wave per block
    const int n0   = blockIdx.x * 16;   // 32 n-tiles
    const int m0   = blockIdx.y * 32;   // 32 m-tiles
    const int lrow = lane & 15;
    const int q    = lane >> 4;         // 0..3

    // Epilogue operands: independent of the K-loop; issue first so their
    // latency hides under the MFMA stream.
    const int ncol = n0 + lrow;
    float xv[2][4];
    #pragma unroll
    for (int mi = 0; mi < 2; ++mi)
        #pragma unroll
        for (int r = 0; r < 4; ++r)
            xv[mi][r] = X[(size_t)(m0 + mi * 16 + q * 4 + r) * LATENT + ncol];
    const float bv = bias[ncol];

    const short* ap0 = Xb + (size_t)(m0 + lrow) * LATENT + q * 8;
    const short* ap1 = ap0 + 16 * LATENT;
    const short* bp0 = Wb + (size_t)(n0 + lrow) * LATENT + q * 8;

    f32x4 acc[2] = {};
    #pragma unroll
    for (int ks = 0; ks < 16; ++ks) {
        bf16x8 a0 = *(const bf16x8*)(ap0 + ks * 32);   // 64B imm offsets
        bf16x8 a1 = *(const bf16x8*)(ap1 + ks * 32);
        bf16x8 b0 = *(const bf16x8*)(bp0 + ks * 32);
        acc[0] = __builtin_amdgcn_mfma_f32_16x16x32_bf16(a0, b0, acc[0], 0, 0, 0);
        acc[1] = __builtin_amdgcn_mfma_f32_16x16x32_bf16(a1, b0, acc[1], 0, 0, 0);
    }

    // Epilogue in fp32: out = x * wx + bias
    #pragma unroll
    for (int mi = 0; mi < 2; ++mi) {
        #pragma unroll
        for (int r = 0; r < 4; ++r) {
            const int m = m0 + mi * 16 + q * 4 + r;
            out[(size_t)m * LATENT + ncol] = xv[mi][r] * acc[mi][r] + bv;
        }
    }
}

extern "C" void kernel_launch(void* const* d_in, const int* in_sizes, int n_in,
                              void* d_out, int out_size, void* d_ws, size_t ws_size,
                              hipStream_t stream) {
    const float* X    = (const float*)d_in[0];   // (1024, 512)
    const float* W    = (const float*)d_in[1];   // (512, 512)
    const float* bias = (const float*)d_in[2];   // (512,)
    float* out        = (float*)d_out;           // (1024, 512)

    short* Xb = (short*)d_ws;                    // 1 MiB
    short* Wb = (short*)d_ws + XN;               // 512 KiB

    convert_kernel<<<(XN + WN) / 8 / 256, 256, 0, stream>>>(X, W, Xb, Wb);
    gemm_kernel<<<dim3(LATENT / 16, BATCH / 32), 64, 0, stream>>>(Xb, Wb, X, bias, out);
}

// Round 3
// 64.800 us; speedup vs baseline: 1.0654x; 1.0141x over previous
//
#include <hip/hip_runtime.h>
#include <stdint.h>

// out[b,i] = x[b,i] * (sum_j x[b,j] * W[i,j]) + bias[i]
// Two-phase (R4 structure — best measured: 63.4 us / 64.4 us):
// (1) convert X,W fp32->bf16 once into ws;
// (2) LDS-free MFMA GEMM, one 64-thread block (1 wave) per 32x32 output
//     tile -> 512 blocks = full 256-CU coverage at 2 waves/CU. Each wave:
//     2x2 16x16x32 bf16 fragments, 4 independent accumulator chains,
//     direct global->register loads (inputs fit in every XCD L2: 1.5 MB),
//     fused fp32 epilogue.
// Session ledger (do not retry):
//  - R5: 64x64 tiles -> 128 blocks -> half the CUs idle. REGRESSED.
//  - R6: single fused kernel, fp32 loads + in-reg cvt_pk. REGRESSED +4.6us
//    (3x GEMM-phase operand traffic; 192 cvt on MFMA critical path; launch
//    savings negligible under graph replay).
//  - R7: 32x16 tile (4 waves/CU) + epilogue prefetch. REGRESSED +1.3us
//    (1.5x loads/MFMA ratio; gemm is load-issue bound, W duplication grew).
// Iteration floor: harness re-poisons 256 MiB ws at ~41us (82% HBM peak,
// unconditional) + ~17us fixed dispatch overhead; kernels are ~5us total.

#define LATENT 512
#define BATCH  1024
#define XN (BATCH * LATENT)    // 524288 floats
#define WN (LATENT * LATENT)   // 262144 floats

typedef short bf16x8 __attribute__((ext_vector_type(8)));   // 8 bf16, 4 VGPRs
typedef float f32x4  __attribute__((ext_vector_type(4)));

__device__ __forceinline__ short f2bf(float f) {
    // RNE fp32 -> bf16 (finite normals)
    uint32_t u = __builtin_bit_cast(uint32_t, f);
    u += 0x7FFFu + ((u >> 16) & 1u);
    return (short)(u >> 16);
}

// ---- Kernel 1: convert X and W to bf16 in ws (each element exactly once) ----
__global__ __launch_bounds__(256) void convert_kernel(
    const float* __restrict__ X, const float* __restrict__ W,
    short* __restrict__ Xb, short* __restrict__ Wb)
{
    const int g = (blockIdx.x * 256 + threadIdx.x) * 8;
    const float* src;
    short* dst;
    if (g < XN) { src = X + g;        dst = Xb + g; }
    else        { src = W + (g - XN); dst = Wb + (g - XN); }
    f32x4 v0 = ((const f32x4*)src)[0];
    f32x4 v1 = ((const f32x4*)src)[1];
    short s[8];
    #pragma unroll
    for (int i = 0; i < 4; ++i) s[i]     = f2bf(v0[i]);
    #pragma unroll
    for (int i = 0; i < 4; ++i) s[4 + i] = f2bf(v1[i]);
    *(bf16x8*)dst = *(bf16x8*)s;
}

// ---- Kernel 2: GEMM C = Xb · Wb^T, 32x32 per wave, fused epilogue ----
// A[m=lane&15][k=q*8+j], B[n=lane&15][k=q*8+j]; rows K-contiguous bf16.
// C/D frag: col = lane&15, row = q*4 + reg.
__global__ __launch_bounds__(64) void gemm_kernel(
    const short* __restrict__ Xb, const short* __restrict__ Wb,
    const float* __restrict__ X, const float* __restrict__ bias,
    float* __restrict__ out)
{
    const int lane = threadIdx.x;       // one wave per block
    const int m0   = blockIdx.y * 32;
    const int n0   = blockIdx.x * 32;
    const int lrow = lane & 15;
    const int q    = lane >> 4;         // 0..3

    const short* ap0 = Xb + (size_t)(m0 + lrow) * LATENT + q * 8;
    const short* ap1 = ap0 + 16 * LATENT;
    const short* bp0 = Wb + (size_t)(n0 + lrow) * LATENT + q * 8;
    const short* bp1 = bp0 + 16 * LATENT;

    f32x4 acc[2][2] = {};
    #pragma unroll
    for (int ks = 0; ks < 16; ++ks) {
        bf16x8 a0 = *(const bf16x8*)(ap0 + ks * 32);   // 64B imm offsets
        bf16x8 a1 = *(const bf16x8*)(ap1 + ks * 32);
        bf16x8 b0 = *(const bf16x8*)(bp0 + ks * 32);
        bf16x8 b1 = *(const bf16x8*)(bp1 + ks * 32);
        acc[0][0] = __builtin_amdgcn_mfma_f32_16x16x32_bf16(a0, b0, acc[0][0], 0, 0, 0);
        acc[0][1] = __builtin_amdgcn_mfma_f32_16x16x32_bf16(a0, b1, acc[0][1], 0, 0, 0);
        acc[1][0] = __builtin_amdgcn_mfma_f32_16x16x32_bf16(a1, b0, acc[1][0], 0, 0, 0);
        acc[1][1] = __builtin_amdgcn_mfma_f32_16x16x32_bf16(a1, b1, acc[1][1], 0, 0, 0);
    }

    // Epilogue in fp32: out = x * wx + bias
    #pragma unroll
    for (int mi = 0; mi < 2; ++mi) {
        #pragma unroll
        for (int ni = 0; ni < 2; ++ni) {
            #pragma unroll
            for (int r = 0; r < 4; ++r) {
                const int m = m0 + mi * 16 + q * 4 + r;
                const int n = n0 + ni * 16 + lrow;
                out[(size_t)m * LATENT + n] =
                    X[(size_t)m * LATENT + n] * acc[mi][ni][r] + bias[n];
            }
        }
    }
}

extern "C" void kernel_launch(void* const* d_in, const int* in_sizes, int n_in,
                              void* d_out, int out_size, void* d_ws, size_t ws_size,
                              hipStream_t stream) {
    const float* X    = (const float*)d_in[0];   // (1024, 512)
    const float* W    = (const float*)d_in[1];   // (512, 512)
    const float* bias = (const float*)d_in[2];   // (512,)
    float* out        = (float*)d_out;           // (1024, 512)

    short* Xb = (short*)d_ws;                    // 1 MiB
    short* Wb = (short*)d_ws + XN;               // 512 KiB

    convert_kernel<<<(XN + WN) / 8 / 256, 256, 0, stream>>>(X, W, Xb, Wb);
    gemm_kernel<<<dim3(LATENT / 32, BATCH / 32), 64, 0, stream>>>(Xb, Wb, X, bias, out);
}